// Round 5
// baseline (159.124 us; speedup 1.0000x reference)
//
#include <hip/hip_runtime.h>
#include <hip/hip_bf16.h>
#include <cstdint>
#include <cstddef>

// LocalMSA fused v8: full switch to v_mfma_f32_32x32x16_bf16 (from 16x16x32).
// Same FLOP, HALF the MFMA instruction count (224->112/wave), half the LDS-read
// instrs per FLOP, 8x dwordx4 output stores (vs 32 dword), softmax denominator
// in 1 shfl_xor (S^T D-layout: each lane owns a single q = lane&31).
// Correctness posture: every MFMA has BOTH operands packed by us under one
// shared (lane-half, elem)->k convention => result independent of HW A/B
// k-wiring; only the m74/m101-verified C/D map (col=lane&31,
// row=(reg&3)+8*(reg>>2)+4*(lane>>5)) is relied on. The 4*(lane>>5) row split
// is bridged by permlane32_swap packs (T12) for both Q^T and P fragments.
// Ks[256][64] / Vt[64][256] LDS layouts stay PHYSICAL (no column permutation).
// Wave w owns q rows AND key rows 32w..32w+31. Key order c2-ascending kept.
// Sentinels: dispatch-1 WRITE_SIZE ~149K KB (no spill), occupancy >=40%,
// FETCH ~140MB, absmax ~0.0059 level (bit-match not expected: k-order changed).

typedef __attribute__((ext_vector_type(8))) short v8s;
typedef __attribute__((ext_vector_type(4))) float v4f;
typedef __attribute__((ext_vector_type(16))) float v16f;
typedef __attribute__((ext_vector_type(4))) unsigned short v4u;
typedef __attribute__((ext_vector_type(4))) unsigned int v4i;

#define MFMA32(a, b, c) __builtin_amdgcn_mfma_f32_32x32x16_bf16((a), (b), (c), 0, 0, 0)

constexpr int LL = 256;
constexpr int CC = 128;
constexpr int CH = 64;
constexpr int KS_BYTES = 256 * 128;   // Ks [256 key][64 cc] bf16, 128B rows
constexpr int VT_BYTES = 64 * 512;    // Vt [64 cc][256 key] bf16, 512B rows

__device__ __forceinline__ unsigned short f2bf(float f) {
    union { __hip_bfloat16 b; unsigned short u; } cv;
    cv.b = __float2bfloat16(f);
    return cv.u;
}

// packed pair f32x2 -> bf16x2 (v_cvt_pk_bf16_f32; RNE == __float2bfloat16)
__device__ __forceinline__ unsigned int pk2(float lo, float hi) {
    union { __hip_bfloat162 b; unsigned int u; } cv;
    cv.b = __float22bfloat162_rn(float2{lo, hi});
    return cv.u;
}

__device__ __forceinline__ v8s load8_f32_bf16(const float* __restrict__ p) {
    float4 a = *reinterpret_cast<const float4*>(p);
    float4 b = *reinterpret_cast<const float4*>(p + 4);
    union { v4i i; v8s s; } u;
    u.i[0] = pk2(a.x, a.y);
    u.i[1] = pk2(a.z, a.w);
    u.i[2] = pk2(b.x, b.y);
    u.i[3] = pk2(b.z, b.w);
    return u.s;
}

__device__ __forceinline__ int swz128(int row, int byte_in_row) {
    return row * 128 + (byte_in_row ^ ((row & 7) << 4));
}
__device__ __forceinline__ int swz512(int row, int byte_in_row) {
    return row * 512 + (byte_in_row ^ ((row & 7) << 4));
}

// Pack 8 f32 (regs 8c..8c+7 of a 32x32 D-tile) into a B-frag v8s whose
// slot e holds k = 16c + 8*(lane>>5) + e, via 4 cvt_pk + 2 permlane32_swap.
// Derivation (C/D row = (reg&3)+8*(reg>>2)+4*h):
//   h=0: e0-3 = own d0,d1 (regs 8c+0..3); e4-7 = partner's d0,d1.
//   h=1: e0-3 = partner's d2,d3 (its regs 8c+4..7); e4-7 = own d2,d3.
// {e0,e2} = swap(d0,d2); {e1,e3} = swap(d1,d3)  (both orientations verified).
__device__ __forceinline__ v8s pack_swap8(float a0, float a1, float a2, float a3,
                                          float a4, float a5, float a6, float a7) {
    int d0 = (int)pk2(a0, a1), d1 = (int)pk2(a2, a3);
    int d2 = (int)pk2(a4, a5), d3 = (int)pk2(a6, a7);
    auto r02 = __builtin_amdgcn_permlane32_swap(d0, d2, false, false);
    auto r13 = __builtin_amdgcn_permlane32_swap(d1, d3, false, false);
    union { v4i i4; v8s s8; } u;
    u.i4[0] = (unsigned)r02[0];
    u.i4[1] = (unsigned)r13[0];
    u.i4[2] = (unsigned)r02[1];
    u.i4[3] = (unsigned)r13[1];
    return u.s8;
}

// W fp32 -> bf16; Q rows (0..127) pre-scaled by 1/sqrt(128)
__global__ __launch_bounds__(256) void wconv_kernel(
    const float* __restrict__ W, unsigned short* __restrict__ Wb)
{
    int i = blockIdx.x * 256 + threadIdx.x;
    float4 v = reinterpret_cast<const float4*>(W)[i];
    const float s = (i < 4096) ? 0.08838834764831845f : 1.0f;
    v4u o;
    o[0] = f2bf(v.x * s); o[1] = f2bf(v.y * s); o[2] = f2bf(v.z * s); o[3] = f2bf(v.w * s);
    reinterpret_cast<v4u*>(Wb)[i] = o;
}

__global__ __launch_bounds__(512, 4) void lmsa_kernel(
    const float* __restrict__ x, const unsigned short* __restrict__ Wb,
    const float* __restrict__ bias, float* __restrict__ out)
{
    __shared__ char smem[KS_BYTES + VT_BYTES];   // 64 KB static
    char* KsB = smem;
    char* VtB = smem + KS_BYTES;

    const int bgh  = blockIdx.x;
    const int bg   = bgh >> 1;
    const int h    = bgh & 1;
    const int tid  = threadIdx.x;
    const int wave = tid >> 6;
    const int lane = tid & 63;
    const int q31  = lane & 31;     // A/B row-col index; this lane's q (and cc/key slot)
    const int hh   = lane >> 5;     // lane half: k-offset 8*hh, D-row offset 4*hh

    const float* xB = x + (size_t)bg * (LL * CC);
    const size_t obase0 = (size_t)bg * (LL * CC);

    const unsigned short* Wq = Wb + (0 * CC + h * CH) * CC;   // pre-scaled
    const unsigned short* Wk = Wb + (1 * CC + h * CH) * CC;
    const unsigned short* Wv = Wb + (2 * CC + h * CH) * CC;
    const float* bq = bias + 0 * CC + h * CH;
    const float* bk = bias + 1 * CC + h * CH;
    const float* bv = bias + 2 * CC + h * CH;

    const float qscale = 0.08838834764831845f;

    // x fragments: slot (hh,e) of af[ks] = x[32w+q31][16ks + 8hh + e]
    v8s af[8];
    #pragma unroll
    for (int ks = 0; ks < 8; ++ks)
        af[ks] = load8_f32_bf16(xB + (32 * wave + q31) * CC + 16 * ks + 8 * hh);

    // ---- K proj: D_K[key' = (r&3)+8(r>>2)+4hh][cc = 32t+q31] ----
    #pragma unroll
    for (int t = 0; t < 2; ++t) {
        v16f acc = {0,0,0,0, 0,0,0,0, 0,0,0,0, 0,0,0,0};
        #pragma unroll
        for (int ks = 0; ks < 8; ++ks) {
            v8s wkf = *reinterpret_cast<const v8s*>(Wk + (32 * t + q31) * CC + 16 * ks + 8 * hh);
            acc = MFMA32(af[ks], wkf, acc);
        }
        const float bkv = bk[32 * t + q31];
        const int cb = (32 * t + q31) << 1;
        #pragma unroll
        for (int r = 0; r < 16; ++r) {
            const int key = 32 * wave + (r & 3) + 8 * (r >> 2) + 4 * hh;
            *(unsigned short*)(KsB + swz128(key, cb)) = f2bf(acc[r] + bkv);
        }
    }

    // ---- V proj: D_V[cc' = (r&3)+8(r>>2)+4hh (+32t)][key = 32w+q31] ----
    #pragma unroll
    for (int t = 0; t < 2; ++t) {
        v16f acc = {0,0,0,0, 0,0,0,0, 0,0,0,0, 0,0,0,0};
        #pragma unroll
        for (int ks = 0; ks < 8; ++ks) {
            v8s wvf = *reinterpret_cast<const v8s*>(Wv + (32 * t + q31) * CC + 16 * ks + 8 * hh);
            acc = MFMA32(wvf, af[ks], acc);
        }
        v4f bv4[4];
        #pragma unroll
        for (int b = 0; b < 4; ++b)
            bv4[b] = *reinterpret_cast<const v4f*>(bv + 32 * t + 8 * b + 4 * hh);
        const int kb = (32 * wave + q31) << 1;
        #pragma unroll
        for (int r = 0; r < 16; ++r) {
            const int cc = 32 * t + (r & 3) + 8 * (r >> 2) + 4 * hh;
            *(unsigned short*)(VtB + swz512(cc, kb)) = f2bf(acc[r] + bv4[r >> 2][r & 3]);
        }
    }

    // ---- Q proj + pack: qB[s] slot e <-> cc = 16s + 8hh + e ----
    v8s qB[4];
    #pragma unroll
    for (int t = 0; t < 2; ++t) {
        v16f acc = {0,0,0,0, 0,0,0,0, 0,0,0,0, 0,0,0,0};
        #pragma unroll
        for (int ks = 0; ks < 8; ++ks) {
            v8s wqf = *reinterpret_cast<const v8s*>(Wq + (32 * t + q31) * CC + 16 * ks + 8 * hh);
            acc = MFMA32(wqf, af[ks], acc);
        }
        v4f bq4[4];
        #pragma unroll
        for (int b = 0; b < 4; ++b)
            bq4[b] = *reinterpret_cast<const v4f*>(bq + 32 * t + 8 * b + 4 * hh);
        float qv[16];
        #pragma unroll
        for (int r = 0; r < 16; ++r)
            qv[r] = acc[r] + bq4[r >> 2][r & 3] * qscale;   // Wq pre-scaled
        qB[2 * t + 0] = pack_swap8(qv[0], qv[1], qv[2], qv[3], qv[4], qv[5], qv[6], qv[7]);
        qB[2 * t + 1] = pack_swap8(qv[8], qv[9], qv[10], qv[11], qv[12], qv[13], qv[14], qv[15]);
    }

    __syncthreads();

    // ------- attention: per c2 (32 keys): S^T = K.Q^T (4 MFMA), exp,
    //         pack P^T (2x pack_swap8), PV: O^T += Vt.P^T (4 MFMA) -------
    v16f o0 = {0,0,0,0, 0,0,0,0, 0,0,0,0, 0,0,0,0};
    v16f o1 = {0,0,0,0, 0,0,0,0, 0,0,0,0, 0,0,0,0};
    float sm = 0.f;

    #pragma unroll 2
    for (int c2 = 0; c2 < 8; ++c2) {
        // A-frags: K rows (lane q31 -> key' = q31) and Vt rows (cc = q31 + 32ccT)
        v8s ksf[4], vtf[4];
        #pragma unroll
        for (int s = 0; s < 4; ++s)
            ksf[s] = *reinterpret_cast<const v8s*>(
                KsB + swz128(32 * c2 + q31, 32 * s + 16 * hh));
        vtf[0] = *reinterpret_cast<const v8s*>(VtB + swz512(q31,      64 * c2 +  0 + 16 * hh));
        vtf[1] = *reinterpret_cast<const v8s*>(VtB + swz512(q31,      64 * c2 + 32 + 16 * hh));
        vtf[2] = *reinterpret_cast<const v8s*>(VtB + swz512(q31 + 32, 64 * c2 +  0 + 16 * hh));
        vtf[3] = *reinterpret_cast<const v8s*>(VtB + swz512(q31 + 32, 64 * c2 + 32 + 16 * hh));

        v16f sa = {0,0,0,0, 0,0,0,0, 0,0,0,0, 0,0,0,0};
        #pragma unroll
        for (int s = 0; s < 4; ++s) sa = MFMA32(ksf[s], qB[s], sa);

        // exp; sm per lane is all-same-q (q = q31): plain serial adds
        float p[16];
        #pragma unroll
        for (int r = 0; r < 16; ++r) p[r] = __expf(sa[r]);
        #pragma unroll
        for (int r = 0; r < 16; ++r) sm += p[r];

        const v8s pB0 = pack_swap8(p[0], p[1], p[2], p[3], p[4], p[5], p[6], p[7]);
        const v8s pB1 = pack_swap8(p[8], p[9], p[10], p[11], p[12], p[13], p[14], p[15]);

        __builtin_amdgcn_s_setprio(1);
        o0 = MFMA32(vtf[0], pB0, o0);
        o0 = MFMA32(vtf[1], pB1, o0);
        o1 = MFMA32(vtf[2], pB0, o1);
        o1 = MFMA32(vtf[3], pB1, o1);
        __builtin_amdgcn_s_setprio(0);
    }

    // ------- normalize + store: lane owns q = 32*wave + q31 entirely -------
    sm += __shfl_xor(sm, 32, 64);
    const float inv = 1.0f / sm;

    float* op = out + obase0 + (size_t)(32 * wave + q31) * CC + h * CH;
    #pragma unroll
    for (int b = 0; b < 4; ++b) {
        v4f v0, v1;
        #pragma unroll
        for (int a = 0; a < 4; ++a) {
            v0[a] = o0[4 * b + a] * inv;   // cc = a + 8b + 4hh
            v1[a] = o1[4 * b + a] * inv;   // cc = a + 8b + 4hh + 32
        }
        *reinterpret_cast<v4f*>(op +  0 + 8 * b + 4 * hh) = v0;
        *reinterpret_cast<v4f*>(op + 32 + 8 * b + 4 * hh) = v1;
    }
}

extern "C" void kernel_launch(void* const* d_in, const int* in_sizes, int n_in,
                              void* d_out, int out_size, void* d_ws, size_t ws_size,
                              hipStream_t stream) {
    (void)in_sizes; (void)n_in; (void)ws_size; (void)out_size;
    const float* x = (const float*)d_in[0];
    const float* W = (const float*)d_in[1];
    const float* b = (const float*)d_in[2];
    float* out = (float*)d_out;
    unsigned short* Wb = (unsigned short*)d_ws;   // 96 KB bf16 W (Q rows pre-scaled)

    wconv_kernel<<<dim3(48), dim3(256), 0, stream>>>(W, Wb);
    lmsa_kernel<<<dim3(2048), dim3(512), 0, stream>>>(x, Wb, b, out);
}

// Round 7
// 158.897 us; speedup vs baseline: 1.0014x; 1.0014x over previous
//
#include <hip/hip_runtime.h>
#include <hip/hip_bf16.h>
#include <cstdint>
#include <cstddef>

// LocalMSA fused v9b: v7 base (150.5us known-good: 16x16x32 MFMA, 64KB LDS,
// (512,4), c2-outer/chk-inner, cvt_pk packs) + three critical-path cuts:
//  1) log2(e) folded into Wq pre-scale + bq factor -> v_exp_f32 direct
//     (__builtin_amdgcn_exp2f; NOT __exp2f which collides with glibc math.h),
//     deleting 128 serial v_mul/wave from the S->exp->pack->PV chain.
//  2) softmax partial sum is a pairwise TREE (was pinned 8-deep serial chain).
//  3) c2 loop fully unrolled -> single straight-line attention block; the
//     scheduler hoists next-chunk ds_reads / interleaves the 2 chk chains
//     as far as the (512,4) 128-reg budget allows (no forced double-buffer).
// v8 lesson applied: keep 16x16x32 shape (32x32 regressed: 2x bank conflicts,
// longer MFMA latency, permlane glue on the critical path).
// Sentinels: dispatch-1 WRITE_SIZE ~139-150K KB (no spill), VGPR ~64,
// LDS 65536, occupancy ~42%, bank conflict ~2.1M, absmax ~0.00586.

typedef __attribute__((ext_vector_type(8))) short v8s;
typedef __attribute__((ext_vector_type(4))) float v4f;
typedef __attribute__((ext_vector_type(4))) unsigned short v4u;
typedef __attribute__((ext_vector_type(4))) unsigned int v4i;

#define MFMA16(a, b, c) __builtin_amdgcn_mfma_f32_16x16x32_bf16((a), (b), (c), 0, 0, 0)

constexpr int LL = 256;
constexpr int CC = 128;
constexpr int CH = 64;
constexpr int KS_BYTES = 256 * 128;   // Ks [256 l][64 cc-slot] bf16, 128B rows
constexpr int VT_BYTES = 64 * 512;    // Vt [64 cc][256 l-slot] bf16, 512B rows

// 1/sqrt(128) and 1/sqrt(128)*log2(e): Q pre-scale so QK^T lands in the
// log2 domain -> one v_exp_f32, no multiply.
constexpr float QSCALE2 = 0.08838834764831845f * 1.4426950408889634f;

__device__ __forceinline__ unsigned short f2bf(float f) {
    union { __hip_bfloat16 b; unsigned short u; } cv;
    cv.b = __float2bfloat16(f);
    return cv.u;
}

// packed pair f32x2 -> bf16x2 (v_cvt_pk_bf16_f32; RNE == __float2bfloat16)
__device__ __forceinline__ unsigned int pk2(float lo, float hi) {
    union { __hip_bfloat162 b; unsigned int u; } cv;
    cv.b = __float22bfloat162_rn(float2{lo, hi});
    return cv.u;
}

__device__ __forceinline__ v8s load8_f32_bf16(const float* __restrict__ p) {
    float4 a = *reinterpret_cast<const float4*>(p);
    float4 b = *reinterpret_cast<const float4*>(p + 4);
    union { v4i i; v8s s; } u;
    u.i[0] = pk2(a.x, a.y);
    u.i[1] = pk2(a.z, a.w);
    u.i[2] = pk2(b.x, b.y);
    u.i[3] = pk2(b.z, b.w);
    return u.s;
}

__device__ __forceinline__ int swz128(int row, int byte_in_row) {
    return row * 128 + (byte_in_row ^ ((row & 7) << 4));
}
__device__ __forceinline__ int swz512(int row, int byte_in_row) {
    return row * 512 + (byte_in_row ^ ((row & 7) << 4));
}

// W fp32 -> bf16; Q rows (0..127) pre-scaled by 1/sqrt(128)*log2(e)
__global__ __launch_bounds__(256) void wconv_kernel(
    const float* __restrict__ W, unsigned short* __restrict__ Wb)
{
    int i = blockIdx.x * 256 + threadIdx.x;
    float4 v = reinterpret_cast<const float4*>(W)[i];
    const float s = (i < 4096) ? QSCALE2 : 1.0f;
    v4u o;
    o[0] = f2bf(v.x * s); o[1] = f2bf(v.y * s); o[2] = f2bf(v.z * s); o[3] = f2bf(v.w * s);
    reinterpret_cast<v4u*>(Wb)[i] = o;
}

__global__ __launch_bounds__(512, 4) void lmsa_kernel(
    const float* __restrict__ x, const unsigned short* __restrict__ Wb,
    const float* __restrict__ bias, float* __restrict__ out)
{
    __shared__ char smem[KS_BYTES + VT_BYTES];   // 64 KB static
    char* KsB = smem;
    char* VtB = smem + KS_BYTES;

    const int bgh  = blockIdx.x;
    const int bg   = bgh >> 1;
    const int h    = bgh & 1;
    const int tid  = threadIdx.x;
    const int wave = tid >> 6;
    const int lane = tid & 63;
    const int m_   = lane & 15;
    const int g    = lane >> 4;
    const int pm   = 8 * (m_ >> 2) + (m_ & 3);   // within-32 slot base

    const float* xB = x + (size_t)bg * (LL * CC);
    const size_t obase0 = (size_t)bg * (LL * CC);

    const unsigned short* Wq = Wb + (0 * CC + h * CH) * CC;   // pre-scaled (incl log2e)
    const unsigned short* Wk = Wb + (1 * CC + h * CH) * CC;
    const unsigned short* Wv = Wb + (2 * CC + h * CH) * CC;
    const float* bq = bias + 0 * CC + h * CH;
    const float* bk = bias + 1 * CC + h * CH;
    const float* bv = bias + 2 * CC + h * CH;

    // K bias hoist (indexed by col = 16nt+m_)
    float bkr[4];
    #pragma unroll
    for (int nt = 0; nt < 4; ++nt) bkr[nt] = bk[16 * nt + m_];

    // x fragments for this wave's rows [32w, 32w+32)
    v8s af[2][4];
    #pragma unroll
    for (int i = 0; i < 2; ++i)
        #pragma unroll
        for (int ks = 0; ks < 4; ++ks)
            af[i][ks] = load8_f32_bf16(xB + (32 * wave + 16 * i + m_) * CC + 32 * ks + 8 * g);

    // ---- K section: D[l][cc]; row=l=16(2w+i)+4g+r, phys cc=16nt+m_ -> permuted ----
    #pragma unroll 2
    for (int nt = 0; nt < 4; ++nt) {
        v8s bf[4];
        #pragma unroll
        for (int ks = 0; ks < 4; ++ks)
            bf[ks] = *reinterpret_cast<const v8s*>(Wk + (16 * nt + m_) * CC + 32 * ks + 8 * g);
        const int kcol = (32 * (nt >> 1) + 4 * (nt & 1) + pm) << 1;
        #pragma unroll
        for (int i = 0; i < 2; ++i) {
            v4f acc = {0.f, 0.f, 0.f, 0.f};
            #pragma unroll
            for (int ks = 0; ks < 4; ++ks) acc = MFMA16(af[i][ks], bf[ks], acc);
            const int row0 = 16 * (2 * wave + i) + 4 * g;
            const unsigned int d0 = pk2(acc[0] + bkr[nt], acc[1] + bkr[nt]);
            const unsigned int d1 = pk2(acc[2] + bkr[nt], acc[3] + bkr[nt]);
            *(unsigned short*)(KsB + swz128(row0 + 0, kcol)) = (unsigned short)d0;
            *(unsigned short*)(KsB + swz128(row0 + 1, kcol)) = (unsigned short)(d0 >> 16);
            *(unsigned short*)(KsB + swz128(row0 + 2, kcol)) = (unsigned short)d1;
            *(unsigned short*)(KsB + swz128(row0 + 3, kcol)) = (unsigned short)(d1 >> 16);
        }
    }

    // ---- Q^T section: D[cc][q]; row=cc=16mtc+4g+r, col=q=16(2w+i)+m_ ----
    v8s qf[2][2];
    #pragma unroll
    for (int i = 0; i < 2; ++i) {
        v4f qacc[4];
        #pragma unroll
        for (int mtc = 0; mtc < 4; ++mtc) {
            v4f acc = {0.f, 0.f, 0.f, 0.f};
            #pragma unroll
            for (int ks = 0; ks < 4; ++ks) {
                v8s wf = *reinterpret_cast<const v8s*>(Wq + (16 * mtc + m_) * CC + 32 * ks + 8 * g);
                acc = MFMA16(wf, af[i][ks], acc);
            }
            #pragma unroll
            for (int r = 0; r < 4; ++r)
                qacc[mtc][r] = acc[r] + bq[16 * mtc + 4 * g + r] * QSCALE2;  // Wq pre-scaled
        }
        // pack B-frag: slot 8g+j <-> phys cc 32ks+16(j>>2)+4g+(j&3); pairs are
        // (qacc[mtc][0],[1]) and ([2],[3]) -> direct cvt_pk dwords
        #pragma unroll
        for (int ks = 0; ks < 2; ++ks) {
            union { v4i i4; v8s s8; } u;
            u.i4[0] = pk2(qacc[2 * ks][0],     qacc[2 * ks][1]);
            u.i4[1] = pk2(qacc[2 * ks][2],     qacc[2 * ks][3]);
            u.i4[2] = pk2(qacc[2 * ks + 1][0], qacc[2 * ks + 1][1]);
            u.i4[3] = pk2(qacc[2 * ks + 1][2], qacc[2 * ks + 1][3]);
            qf[i][ks] = u.s8;
        }
    }

    // ---- Vt section: D[cc][l]; row=cc=16mtc+4g+r, phys l=16(2w+i)+m_ -> permuted ----
    #pragma unroll 2
    for (int mtc = 0; mtc < 4; ++mtc) {
        v8s wf[4];
        #pragma unroll
        for (int ks = 0; ks < 4; ++ks)
            wf[ks] = *reinterpret_cast<const v8s*>(Wv + (16 * mtc + m_) * CC + 32 * ks + 8 * g);
        v4f bvv = *reinterpret_cast<const v4f*>(bv + 16 * mtc + 4 * g);
        #pragma unroll
        for (int i = 0; i < 2; ++i) {
            const int mt = 2 * wave + i;
            const int vcol = (32 * (mt >> 1) + 4 * (mt & 1) + pm) << 1;
            v4f acc = {0.f, 0.f, 0.f, 0.f};
            #pragma unroll
            for (int ks = 0; ks < 4; ++ks) acc = MFMA16(wf[ks], af[i][ks], acc);
            const int row0 = 16 * mtc + 4 * g;
            const unsigned int d0 = pk2(acc[0] + bvv[0], acc[1] + bvv[1]);
            const unsigned int d1 = pk2(acc[2] + bvv[2], acc[3] + bvv[3]);
            *(unsigned short*)(VtB + swz512(row0 + 0, vcol)) = (unsigned short)d0;
            *(unsigned short*)(VtB + swz512(row0 + 1, vcol)) = (unsigned short)(d0 >> 16);
            *(unsigned short*)(VtB + swz512(row0 + 2, vcol)) = (unsigned short)d1;
            *(unsigned short*)(VtB + swz512(row0 + 3, vcol)) = (unsigned short)(d1 >> 16);
        }
    }

    __syncthreads();

    // ------- attention: c2 outer (shared kf/vf reads), chk inner (2 chains),
    //         FULLY UNROLLED so the scheduler pipelines across chunks -------
    v4f o[2][4];
    #pragma unroll
    for (int chk = 0; chk < 2; ++chk)
        #pragma unroll
        for (int nt = 0; nt < 4; ++nt) o[chk][nt] = v4f{0.f, 0.f, 0.f, 0.f};
    float sm[2] = {0.f, 0.f};

    #pragma unroll
    for (int c2 = 0; c2 < 8; ++c2) {       // 8 key-chunks of 32
        // shared LDS reads for this chunk (used by BOTH chk chains)
        v8s kf0[2], kf1[2], vf[4];
        #pragma unroll
        for (int ks = 0; ks < 2; ++ks)
            kf0[ks] = *reinterpret_cast<const v8s*>(
                KsB + swz128(32 * c2 + m_, (32 * ks + 8 * g) << 1));
        #pragma unroll
        for (int ks = 0; ks < 2; ++ks)
            kf1[ks] = *reinterpret_cast<const v8s*>(
                KsB + swz128(32 * c2 + 16 + m_, (32 * ks + 8 * g) << 1));
        #pragma unroll
        for (int nt = 0; nt < 4; ++nt)
            vf[nt] = *reinterpret_cast<const v8s*>(
                VtB + swz512(16 * nt + m_, 64 * c2 + 16 * g));

        #pragma unroll
        for (int chk = 0; chk < 2; ++chk) {
            v4f s0 = {0.f, 0.f, 0.f, 0.f}, s1 = {0.f, 0.f, 0.f, 0.f};
            #pragma unroll
            for (int ks = 0; ks < 2; ++ks) s0 = MFMA16(kf0[ks], qf[chk][ks], s0);
            #pragma unroll
            for (int ks = 0; ks < 2; ++ks) s1 = MFMA16(kf1[ks], qf[chk][ks], s1);

            // lane(m_,g): P[q=m_][k=32c2+16t+4g+r]; A-frag slot 8g+j: t=j>>2, r=j&3
            // S is already in log2 domain (Q pre-scaled by log2e): v_exp_f32 direct.
            const float p0 = __builtin_amdgcn_exp2f(s0[0]);
            const float p1 = __builtin_amdgcn_exp2f(s0[1]);
            const float p2 = __builtin_amdgcn_exp2f(s0[2]);
            const float p3 = __builtin_amdgcn_exp2f(s0[3]);
            const float p4 = __builtin_amdgcn_exp2f(s1[0]);
            const float p5 = __builtin_amdgcn_exp2f(s1[1]);
            const float p6 = __builtin_amdgcn_exp2f(s1[2]);
            const float p7 = __builtin_amdgcn_exp2f(s1[3]);
            // pairwise tree (breaks the old 8-deep serial chain)
            sm[chk] += ((p0 + p1) + (p2 + p3)) + ((p4 + p5) + (p6 + p7));
            union { v4i i4; v8s s8; } up;
            up.i4[0] = pk2(p0, p1);
            up.i4[1] = pk2(p2, p3);
            up.i4[2] = pk2(p4, p5);
            up.i4[3] = pk2(p6, p7);
            const v8s pf = up.s8;

            __builtin_amdgcn_s_setprio(1);
            #pragma unroll
            for (int nt = 0; nt < 4; ++nt)
                o[chk][nt] = MFMA16(pf, vf[nt], o[chk][nt]);
            __builtin_amdgcn_s_setprio(0);
        }
    }

    // ------- normalize + store: q rows = 32*wave + 16*chk + 4g + r -------
    #pragma unroll
    for (int chk = 0; chk < 2; ++chk) {
        float s = sm[chk];
        s += __shfl_xor(s, 16, 64);
        s += __shfl_xor(s, 32, 64);
        float inv[4];
        #pragma unroll
        for (int r = 0; r < 4; ++r) inv[r] = 1.0f / __shfl(s, 4 * g + r, 64);

        const int rowb = 32 * wave + 16 * chk;
        #pragma unroll
        for (int nt = 0; nt < 4; ++nt)
            #pragma unroll
            for (int r = 0; r < 4; ++r)
                out[obase0 + (size_t)(rowb + 4 * g + r) * CC + h * CH + 16 * nt + m_] =
                    o[chk][nt][r] * inv[r];
    }
}

extern "C" void kernel_launch(void* const* d_in, const int* in_sizes, int n_in,
                              void* d_out, int out_size, void* d_ws, size_t ws_size,
                              hipStream_t stream) {
    (void)in_sizes; (void)n_in; (void)ws_size; (void)out_size;
    const float* x = (const float*)d_in[0];
    const float* W = (const float*)d_in[1];
    const float* b = (const float*)d_in[2];
    float* out = (float*)d_out;
    unsigned short* Wb = (unsigned short*)d_ws;   // 96 KB bf16 W (Q rows pre-scaled)

    wconv_kernel<<<dim3(48), dim3(256), 0, stream>>>(W, Wb);
    lmsa_kernel<<<dim3(2048), dim3(512), 0, stream>>>(x, Wb, b, out);
}

// Round 8
// 151.241 us; speedup vs baseline: 1.0521x; 1.0506x over previous
//
#include <hip/hip_runtime.h>
#include <hip/hip_bf16.h>
#include <cstdint>
#include <cstddef>

// LocalMSA fused v10: v7 base (150.5us known-good) + exp2 fold + tree-sum,
// WITHOUT v9b's full c2 unroll (which spilled: steady WRITE_SIZE 131K->166K KB,
// dur 158.9). c2 loop back to #pragma unroll 2 = v7's proven register footprint.
//  1) log2(e) folded into Wq pre-scale + bq factor -> v_exp_f32 direct
//     (__builtin_amdgcn_exp2f), deleting 128 serial v_mul/wave from the
//     S->exp->pack->PV critical chain.
//  2) softmax partial sum is a pairwise TREE (was pinned 8-deep serial chain).
// Sentinels: steady WRITE_SIZE back to ~131K KB pattern (no spill!), dispatch-1
// ~149K KB, VGPR 64, LDS 65536, occupancy ~42%, bank conflict ~2.1M,
// absmax ~0.0078 (1 ulp from exp2 domain change).

typedef __attribute__((ext_vector_type(8))) short v8s;
typedef __attribute__((ext_vector_type(4))) float v4f;
typedef __attribute__((ext_vector_type(4))) unsigned short v4u;
typedef __attribute__((ext_vector_type(4))) unsigned int v4i;

#define MFMA16(a, b, c) __builtin_amdgcn_mfma_f32_16x16x32_bf16((a), (b), (c), 0, 0, 0)

constexpr int LL = 256;
constexpr int CC = 128;
constexpr int CH = 64;
constexpr int KS_BYTES = 256 * 128;   // Ks [256 l][64 cc-slot] bf16, 128B rows
constexpr int VT_BYTES = 64 * 512;    // Vt [64 cc][256 l-slot] bf16, 512B rows

// 1/sqrt(128)*log2(e): Q pre-scale so QK^T lands in the log2 domain.
constexpr float QSCALE2 = 0.08838834764831845f * 1.4426950408889634f;

__device__ __forceinline__ unsigned short f2bf(float f) {
    union { __hip_bfloat16 b; unsigned short u; } cv;
    cv.b = __float2bfloat16(f);
    return cv.u;
}

// packed pair f32x2 -> bf16x2 (v_cvt_pk_bf16_f32; RNE == __float2bfloat16)
__device__ __forceinline__ unsigned int pk2(float lo, float hi) {
    union { __hip_bfloat162 b; unsigned int u; } cv;
    cv.b = __float22bfloat162_rn(float2{lo, hi});
    return cv.u;
}

__device__ __forceinline__ v8s load8_f32_bf16(const float* __restrict__ p) {
    float4 a = *reinterpret_cast<const float4*>(p);
    float4 b = *reinterpret_cast<const float4*>(p + 4);
    union { v4i i; v8s s; } u;
    u.i[0] = pk2(a.x, a.y);
    u.i[1] = pk2(a.z, a.w);
    u.i[2] = pk2(b.x, b.y);
    u.i[3] = pk2(b.z, b.w);
    return u.s;
}

__device__ __forceinline__ int swz128(int row, int byte_in_row) {
    return row * 128 + (byte_in_row ^ ((row & 7) << 4));
}
__device__ __forceinline__ int swz512(int row, int byte_in_row) {
    return row * 512 + (byte_in_row ^ ((row & 7) << 4));
}

// W fp32 -> bf16; Q rows (0..127) pre-scaled by 1/sqrt(128)*log2(e)
__global__ __launch_bounds__(256) void wconv_kernel(
    const float* __restrict__ W, unsigned short* __restrict__ Wb)
{
    int i = blockIdx.x * 256 + threadIdx.x;
    float4 v = reinterpret_cast<const float4*>(W)[i];
    const float s = (i < 4096) ? QSCALE2 : 1.0f;
    v4u o;
    o[0] = f2bf(v.x * s); o[1] = f2bf(v.y * s); o[2] = f2bf(v.z * s); o[3] = f2bf(v.w * s);
    reinterpret_cast<v4u*>(Wb)[i] = o;
}

__global__ __launch_bounds__(512, 4) void lmsa_kernel(
    const float* __restrict__ x, const unsigned short* __restrict__ Wb,
    const float* __restrict__ bias, float* __restrict__ out)
{
    __shared__ char smem[KS_BYTES + VT_BYTES];   // 64 KB static
    char* KsB = smem;
    char* VtB = smem + KS_BYTES;

    const int bgh  = blockIdx.x;
    const int bg   = bgh >> 1;
    const int h    = bgh & 1;
    const int tid  = threadIdx.x;
    const int wave = tid >> 6;
    const int lane = tid & 63;
    const int m_   = lane & 15;
    const int g    = lane >> 4;
    const int pm   = 8 * (m_ >> 2) + (m_ & 3);   // within-32 slot base

    const float* xB = x + (size_t)bg * (LL * CC);
    const size_t obase0 = (size_t)bg * (LL * CC);

    const unsigned short* Wq = Wb + (0 * CC + h * CH) * CC;   // pre-scaled (incl log2e)
    const unsigned short* Wk = Wb + (1 * CC + h * CH) * CC;
    const unsigned short* Wv = Wb + (2 * CC + h * CH) * CC;
    const float* bq = bias + 0 * CC + h * CH;
    const float* bk = bias + 1 * CC + h * CH;
    const float* bv = bias + 2 * CC + h * CH;

    // K bias hoist (indexed by col = 16nt+m_)
    float bkr[4];
    #pragma unroll
    for (int nt = 0; nt < 4; ++nt) bkr[nt] = bk[16 * nt + m_];

    // x fragments for this wave's rows [32w, 32w+32)
    v8s af[2][4];
    #pragma unroll
    for (int i = 0; i < 2; ++i)
        #pragma unroll
        for (int ks = 0; ks < 4; ++ks)
            af[i][ks] = load8_f32_bf16(xB + (32 * wave + 16 * i + m_) * CC + 32 * ks + 8 * g);

    // ---- K section: D[l][cc]; row=l=16(2w+i)+4g+r, phys cc=16nt+m_ -> permuted ----
    #pragma unroll 2
    for (int nt = 0; nt < 4; ++nt) {
        v8s bf[4];
        #pragma unroll
        for (int ks = 0; ks < 4; ++ks)
            bf[ks] = *reinterpret_cast<const v8s*>(Wk + (16 * nt + m_) * CC + 32 * ks + 8 * g);
        const int kcol = (32 * (nt >> 1) + 4 * (nt & 1) + pm) << 1;
        #pragma unroll
        for (int i = 0; i < 2; ++i) {
            v4f acc = {0.f, 0.f, 0.f, 0.f};
            #pragma unroll
            for (int ks = 0; ks < 4; ++ks) acc = MFMA16(af[i][ks], bf[ks], acc);
            const int row0 = 16 * (2 * wave + i) + 4 * g;
            const unsigned int d0 = pk2(acc[0] + bkr[nt], acc[1] + bkr[nt]);
            const unsigned int d1 = pk2(acc[2] + bkr[nt], acc[3] + bkr[nt]);
            *(unsigned short*)(KsB + swz128(row0 + 0, kcol)) = (unsigned short)d0;
            *(unsigned short*)(KsB + swz128(row0 + 1, kcol)) = (unsigned short)(d0 >> 16);
            *(unsigned short*)(KsB + swz128(row0 + 2, kcol)) = (unsigned short)d1;
            *(unsigned short*)(KsB + swz128(row0 + 3, kcol)) = (unsigned short)(d1 >> 16);
        }
    }

    // ---- Q^T section: D[cc][q]; row=cc=16mtc+4g+r, col=q=16(2w+i)+m_ ----
    v8s qf[2][2];
    #pragma unroll
    for (int i = 0; i < 2; ++i) {
        v4f qacc[4];
        #pragma unroll
        for (int mtc = 0; mtc < 4; ++mtc) {
            v4f acc = {0.f, 0.f, 0.f, 0.f};
            #pragma unroll
            for (int ks = 0; ks < 4; ++ks) {
                v8s wf = *reinterpret_cast<const v8s*>(Wq + (16 * mtc + m_) * CC + 32 * ks + 8 * g);
                acc = MFMA16(wf, af[i][ks], acc);
            }
            #pragma unroll
            for (int r = 0; r < 4; ++r)
                qacc[mtc][r] = acc[r] + bq[16 * mtc + 4 * g + r] * QSCALE2;  // Wq pre-scaled
        }
        // pack B-frag: slot 8g+j <-> phys cc 32ks+16(j>>2)+4g+(j&3); pairs are
        // (qacc[mtc][0],[1]) and ([2],[3]) -> direct cvt_pk dwords
        #pragma unroll
        for (int ks = 0; ks < 2; ++ks) {
            union { v4i i4; v8s s8; } u;
            u.i4[0] = pk2(qacc[2 * ks][0],     qacc[2 * ks][1]);
            u.i4[1] = pk2(qacc[2 * ks][2],     qacc[2 * ks][3]);
            u.i4[2] = pk2(qacc[2 * ks + 1][0], qacc[2 * ks + 1][1]);
            u.i4[3] = pk2(qacc[2 * ks + 1][2], qacc[2 * ks + 1][3]);
            qf[i][ks] = u.s8;
        }
    }

    // ---- Vt section: D[cc][l]; row=cc=16mtc+4g+r, phys l=16(2w+i)+m_ -> permuted ----
    #pragma unroll 2
    for (int mtc = 0; mtc < 4; ++mtc) {
        v8s wf[4];
        #pragma unroll
        for (int ks = 0; ks < 4; ++ks)
            wf[ks] = *reinterpret_cast<const v8s*>(Wv + (16 * mtc + m_) * CC + 32 * ks + 8 * g);
        v4f bvv = *reinterpret_cast<const v4f*>(bv + 16 * mtc + 4 * g);
        #pragma unroll
        for (int i = 0; i < 2; ++i) {
            const int mt = 2 * wave + i;
            const int vcol = (32 * (mt >> 1) + 4 * (mt & 1) + pm) << 1;
            v4f acc = {0.f, 0.f, 0.f, 0.f};
            #pragma unroll
            for (int ks = 0; ks < 4; ++ks) acc = MFMA16(wf[ks], af[i][ks], acc);
            const int row0 = 16 * mtc + 4 * g;
            const unsigned int d0 = pk2(acc[0] + bvv[0], acc[1] + bvv[1]);
            const unsigned int d1 = pk2(acc[2] + bvv[2], acc[3] + bvv[3]);
            *(unsigned short*)(VtB + swz512(row0 + 0, vcol)) = (unsigned short)d0;
            *(unsigned short*)(VtB + swz512(row0 + 1, vcol)) = (unsigned short)(d0 >> 16);
            *(unsigned short*)(VtB + swz512(row0 + 2, vcol)) = (unsigned short)d1;
            *(unsigned short*)(VtB + swz512(row0 + 3, vcol)) = (unsigned short)(d1 >> 16);
        }
    }

    __syncthreads();

    // ------- attention: c2 outer (shared kf/vf reads), chk inner (2 chains) ---
    v4f o[2][4];
    #pragma unroll
    for (int chk = 0; chk < 2; ++chk)
        #pragma unroll
        for (int nt = 0; nt < 4; ++nt) o[chk][nt] = v4f{0.f, 0.f, 0.f, 0.f};
    float sm[2] = {0.f, 0.f};

    #pragma unroll 2
    for (int c2 = 0; c2 < 8; ++c2) {       // 8 key-chunks of 32
        // shared LDS reads for this chunk (used by BOTH chk chains)
        v8s kf0[2], kf1[2], vf[4];
        #pragma unroll
        for (int ks = 0; ks < 2; ++ks)
            kf0[ks] = *reinterpret_cast<const v8s*>(
                KsB + swz128(32 * c2 + m_, (32 * ks + 8 * g) << 1));
        #pragma unroll
        for (int ks = 0; ks < 2; ++ks)
            kf1[ks] = *reinterpret_cast<const v8s*>(
                KsB + swz128(32 * c2 + 16 + m_, (32 * ks + 8 * g) << 1));
        #pragma unroll
        for (int nt = 0; nt < 4; ++nt)
            vf[nt] = *reinterpret_cast<const v8s*>(
                VtB + swz512(16 * nt + m_, 64 * c2 + 16 * g));

        #pragma unroll
        for (int chk = 0; chk < 2; ++chk) {
            v4f s0 = {0.f, 0.f, 0.f, 0.f}, s1 = {0.f, 0.f, 0.f, 0.f};
            #pragma unroll
            for (int ks = 0; ks < 2; ++ks) s0 = MFMA16(kf0[ks], qf[chk][ks], s0);
            #pragma unroll
            for (int ks = 0; ks < 2; ++ks) s1 = MFMA16(kf1[ks], qf[chk][ks], s1);

            // lane(m_,g): P[q=m_][k=32c2+16t+4g+r]; A-frag slot 8g+j: t=j>>2, r=j&3
            // S is already in log2 domain (Q pre-scaled by log2e): v_exp_f32 direct.
            const float p0 = __builtin_amdgcn_exp2f(s0[0]);
            const float p1 = __builtin_amdgcn_exp2f(s0[1]);
            const float p2 = __builtin_amdgcn_exp2f(s0[2]);
            const float p3 = __builtin_amdgcn_exp2f(s0[3]);
            const float p4 = __builtin_amdgcn_exp2f(s1[0]);
            const float p5 = __builtin_amdgcn_exp2f(s1[1]);
            const float p6 = __builtin_amdgcn_exp2f(s1[2]);
            const float p7 = __builtin_amdgcn_exp2f(s1[3]);
            // pairwise tree (breaks the old 8-deep serial chain)
            sm[chk] += ((p0 + p1) + (p2 + p3)) + ((p4 + p5) + (p6 + p7));
            union { v4i i4; v8s s8; } up;
            up.i4[0] = pk2(p0, p1);
            up.i4[1] = pk2(p2, p3);
            up.i4[2] = pk2(p4, p5);
            up.i4[3] = pk2(p6, p7);
            const v8s pf = up.s8;

            __builtin_amdgcn_s_setprio(1);
            #pragma unroll
            for (int nt = 0; nt < 4; ++nt)
                o[chk][nt] = MFMA16(pf, vf[nt], o[chk][nt]);
            __builtin_amdgcn_s_setprio(0);
        }
    }

    // ------- normalize + store: q rows = 32*wave + 16*chk + 4g + r -------
    #pragma unroll
    for (int chk = 0; chk < 2; ++chk) {
        float s = sm[chk];
        s += __shfl_xor(s, 16, 64);
        s += __shfl_xor(s, 32, 64);
        float inv[4];
        #pragma unroll
        for (int r = 0; r < 4; ++r) inv[r] = 1.0f / __shfl(s, 4 * g + r, 64);

        const int rowb = 32 * wave + 16 * chk;
        #pragma unroll
        for (int nt = 0; nt < 4; ++nt)
            #pragma unroll
            for (int r = 0; r < 4; ++r)
                out[obase0 + (size_t)(rowb + 4 * g + r) * CC + h * CH + 16 * nt + m_] =
                    o[chk][nt][r] * inv[r];
    }
}

extern "C" void kernel_launch(void* const* d_in, const int* in_sizes, int n_in,
                              void* d_out, int out_size, void* d_ws, size_t ws_size,
                              hipStream_t stream) {
    (void)in_sizes; (void)n_in; (void)ws_size; (void)out_size;
    const float* x = (const float*)d_in[0];
    const float* W = (const float*)d_in[1];
    const float* b = (const float*)d_in[2];
    float* out = (float*)d_out;
    unsigned short* Wb = (unsigned short*)d_ws;   // 96 KB bf16 W (Q rows pre-scaled)

    wconv_kernel<<<dim3(48), dim3(256), 0, stream>>>(W, Wb);
    lmsa_kernel<<<dim3(2048), dim3(512), 0, stream>>>(x, Wb, b, out);
}